// Round 20
// baseline (48.005 us; speedup 1.0000x reference)
//
#include <hip/hip_runtime.h>
#include <math.h>

#define BB 4
#define CC 64
#define OO 64
#define HH 128
#define WW 128
#define HWsz (HH * WW)

typedef __attribute__((ext_vector_type(8))) _Float16 half8;
typedef __attribute__((ext_vector_type(4))) float floatx4;

// ---------------------------------------------------------------------------
// pre: (blocks 0..511)  x NCHW f32 -> xh merged NHWC f16 (px = 128B = 1 line)
//      (blocks 512..727) fragment-ordered f16 weight repack:
//  waf[((k*2+kh)*4+m)*512 + lane*8 + j], wcf[((k*2+kh)*2+m)*512 + lane*8 + j]
// ---------------------------------------------------------------------------
__global__ __launch_bounds__(256) void pre_kernel(
    const float* __restrict__ x, const float* __restrict__ wgt,
    const float* __restrict__ ow, const float* __restrict__ mw,
    _Float16* __restrict__ xh, _Float16* __restrict__ waf,
    _Float16* __restrict__ wcf)
{
    int bid = blockIdx.x;
    int tid = threadIdx.x;
    if (bid < 512) {
        int b = bid >> 7, y = bid & 127;
        int px = tid & 127;
        int ch = (tid >> 7) * 32;
        const float* xp = x + (size_t)(b * CC + ch) * HWsz + y * WW + px;
        _Float16 buf[32];
#pragma unroll
        for (int q = 0; q < 32; ++q)
            buf[q] = (_Float16)xp[(size_t)q * HWsz];
        _Float16* dst = xh + ((size_t)(b * HH + y) * WW + px) * 64 + ch;
#pragma unroll
        for (int q = 0; q < 4; ++q)
            *(half8*)&dst[q * 8] = *(const half8*)&buf[q * 8];
    } else {
        int i = (bid - 512) * 256 + tid;
        if (i < 36864) {
            int j = i & 7, lane = (i >> 3) & 63, rest = i >> 9;
            int m = rest & 3, kh = (rest >> 2) & 1, k = rest >> 3;
            int o = m * 16 + (lane & 15);
            int c = kh * 32 + ((lane >> 4) << 3) + j;
            waf[i] = (_Float16)wgt[o * 576 + c * 9 + k];
        } else if (i < 55296) {
            int t = i - 36864;
            int j = t & 7, lane = (t >> 3) & 63, rest = t >> 9;
            int m = rest & 1, kh = (rest >> 1) & 1, k = rest >> 2;
            int o = m * 16 + (lane & 15);
            int c = kh * 32 + ((lane >> 4) << 3) + j;
            float v = 0.f;
            if (o < 18) v = ow[o * 576 + c * 9 + k];
            else if (o < 27) v = mw[(o - 18) * 576 + c * 9 + k];
            wcf[t] = (_Float16)v;
        }
    }
}

// ---------------------------------------------------------------------------
// fused kernel (fp16, LDS phase-1 window + full-line phase-2 gathers).
// 256 blocks x 1024 thr = 1 block/CU, 16 waves = 4 rows x 4 strips x 64-px
// column half.
//   fill:    6x68-px input window (rows h-1..h+4, cols p0-1..p0+64) -> LDS,
//            zero-padded at borders, XOR-swizzled; one barrier.
//   phase 1: offset/mask conv reads window from LDS (zero L1 traffic),
//            weights from global wcf (L1-hot) -> om (f16, wave-local LDS).
//   phase 2: R19 pipeline — full-line gathers (1 visit/px-corner), blend,
//            cross-tap double-buffered LDS bounce; waf weights from global.
// ---------------------------------------------------------------------------
__global__ __launch_bounds__(1024, 1) void fused_kernel(
    const _Float16* __restrict__ xh, const _Float16* __restrict__ waf,
    const _Float16* __restrict__ wcf, const float* __restrict__ ob,
    const float* __restrict__ mb, float* __restrict__ out)
{
    __shared__ __align__(16) _Float16 win[6 * 68 * 64];   // 52224 B
    __shared__ _Float16 omh[16 * 27 * 16];                // 13824 B
    __shared__ __align__(16) _Float16 blendb[16 * 2048];  // 65536 B

    int tid = threadIdx.x;
    int gid = blockIdx.x;
    // XCD swizzle: 256 blocks = 8 XCDs x 32 contiguous region-tiles
    int sid = (gid & 7) * 32 + (gid >> 3);
    int b = sid >> 6;
    int t = sid & 63;
    int rq = t >> 1;
    int q = t & 1;

    int wv = tid >> 6;         // 0..15
    int lane = tid & 63;
    int s = wv & 3;            // strip
    int h = rq * 4 + (wv >> 2);
    int p0 = q << 6;
    int g = lane >> 4;
    int pl = lane & 15;
    int oct = lane & 7;        // phase-2 gather: channel octet
    int pxg = lane >> 3;       // phase-2 gather: pixel within 8-px group
    int h0 = rq * 4;           // block's first output row

    const _Float16* xhb = xh + ((size_t)b << 20);
    _Float16* omw = &omh[wv * 27 * 16];
    _Float16* bbw = &blendb[wv * 2048];

    // ---------------- window fill: rows h0-1..h0+4, cols p0-1..p0+66 -------
    // chunk ch -> (r, c, o8): 16B each; zero outside image; swizzled store.
    {
        half8 z = {0, 0, 0, 0, 0, 0, 0, 0};
#pragma unroll
        for (int it = 0; it < 4; ++it) {
            int ch = tid + it * 1024;
            if (ch < 3264) {
                int o8 = ch & 7;
                int rc = ch >> 3;          // 0..407
                int r = rc / 68;
                int cc = rc - r * 68;
                int gy = h0 - 1 + r;
                int gx = p0 - 1 + cc;
                half8 v = z;
                if ((cc < 66) & (gy >= 0) & (gy < HH) & (gx >= 0) & (gx < WW))
                    v = *(const half8*)(xhb + (((size_t)gy * WW + gx) << 6) + o8 * 8);
                *(half8*)&win[((r * 68 + cc) << 6) + ((o8 ^ (cc & 7)) << 3)] = v;
            }
        }
    }
    __syncthreads();

    // ---------------- phase 1: offset/mask conv from LDS window ------------
    floatx4 accC0 = {0.f, 0.f, 0.f, 0.f};
    floatx4 accC1 = {0.f, 0.f, 0.f, 0.f};

#define CONVTAP(K) do {                                                      \
    int ky = (K) / 3, kx = (K) - ky * 3;                                     \
    int r = (wv >> 2) + ky;                                                  \
    int c = s * 16 + pl + kx;                                                \
    const _Float16* wb = &win[((r * 68 + c) << 6)];                          \
    half8 a0 = *(const half8*)&wb[((g ^ (c & 7)) << 3)];                     \
    half8 a1 = *(const half8*)&wb[(((g + 4) ^ (c & 7)) << 3)];               \
    const _Float16* wp = wcf + ((K) << 11) + lane * 8;                       \
    half8 w00 = *(const half8*)(wp + (0 << 9));                              \
    half8 w01 = *(const half8*)(wp + (1 << 9));                              \
    half8 w10 = *(const half8*)(wp + (2 << 9));                              \
    half8 w11 = *(const half8*)(wp + (3 << 9));                              \
    accC0 = __builtin_amdgcn_mfma_f32_16x16x32_f16(w00, a0, accC0, 0, 0, 0); \
    accC1 = __builtin_amdgcn_mfma_f32_16x16x32_f16(w01, a0, accC1, 0, 0, 0); \
    accC0 = __builtin_amdgcn_mfma_f32_16x16x32_f16(w10, a1, accC0, 0, 0, 0); \
    accC1 = __builtin_amdgcn_mfma_f32_16x16x32_f16(w11, a1, accC1, 0, 0, 0); \
} while (0)

    CONVTAP(0); CONVTAP(1); CONVTAP(2); CONVTAP(3); CONVTAP(4);
    CONVTAP(5); CONVTAP(6); CONVTAP(7); CONVTAP(8);

    // om epilogue (wave-local, f16)
#pragma unroll
    for (int j = 0; j < 4; ++j) {
        int o = g * 4 + j;
        omw[o * 16 + pl] = (_Float16)(accC0[j] + ob[o]);
        int o2 = 16 + g * 4 + j;
        float v = accC1[j];
        if (o2 < 18) omw[o2 * 16 + pl] = (_Float16)(v + ob[o2]);
        else if (o2 < 27)
            omw[o2 * 16 + pl] =
                (_Float16)(1.0f / (1.0f + expf(-(v + mb[o2 - 18]))));
    }

    // ---------------- phase 2: pipelined full-line gathers + GEMM ----------
    floatx4 acc0 = {0.f, 0.f, 0.f, 0.f}, acc1 = {0.f, 0.f, 0.f, 0.f};
    floatx4 acc2 = {0.f, 0.f, 0.f, 0.f}, acc3 = {0.f, 0.f, 0.f, 0.f};

#define MKT(K, P, U00, U01, U10, U11, I00, I01, I10, I11) do {               \
    int ky = (K) / 3, kx = (K) - ky * 3;                                     \
    float oy = (float)omw[(2 * (K)) * 16 + (P)];                             \
    float ox = (float)omw[(2 * (K) + 1) * 16 + (P)];                         \
    float mk = (float)omw[(18 + (K)) * 16 + (P)];                            \
    float py = oy + (float)(h + ky - 1);                                     \
    float qx = ox + (float)(p0 + s * 16 + (P) + kx - 1);                     \
    float y0f = floorf(py), x0f = floorf(qx);                                \
    float dyy = py - y0f, dxx = qx - x0f;                                    \
    int y0 = (int)y0f, x0 = (int)x0f;                                        \
    int y1 = y0 + 1, x1 = x0 + 1;                                            \
    bool vy0 = (y0 >= 0) & (y0 < HH), vy1 = (y1 >= 0) & (y1 < HH);           \
    bool vx0 = (x0 >= 0) & (x0 < WW), vx1 = (x1 >= 0) & (x1 < WW);           \
    U00 = (vy0 & vx0) ? (1.f - dyy) * (1.f - dxx) * mk : 0.f;                \
    U01 = (vy0 & vx1) ? (1.f - dyy) * dxx * mk : 0.f;                        \
    U10 = (vy1 & vx0) ? dyy * (1.f - dxx) * mk : 0.f;                        \
    U11 = (vy1 & vx1) ? dyy * dxx * mk : 0.f;                                \
    int yc0 = min(max(y0, 0), HH - 1), yc1 = min(max(y1, 0), HH - 1);        \
    int xc0 = min(max(x0, 0), WW - 1), xc1 = min(max(x1, 0), WW - 1);        \
    I00 = ((yc0 * WW + xc0) << 6) + oct * 8;                                 \
    I01 = ((yc0 * WW + xc1) << 6) + oct * 8;                                 \
    I10 = ((yc1 * WW + xc0) << 6) + oct * 8;                                 \
    I11 = ((yc1 * WW + xc1) << 6) + oct * 8;                                 \
} while (0)

#define SPLAT8(H) ((half8){(H), (H), (H), (H), (H), (H), (H), (H)})
#define MF(Q, B, A) A = __builtin_amdgcn_mfma_f32_16x16x32_f16(Q, B, A, 0, 0, 0)

#define DECLG(S)                                                             \
    float u0##S, u1##S, u2##S, u3##S, u4##S, u5##S, u6##S, u7##S;            \
    half8 r0##S, r1##S, r2##S, r3##S, r4##S, r5##S, r6##S, r7##S;

#define GLOAD(K, S) do {                                                     \
    int i0, i1, i2, i3, i4, i5, i6, i7;                                      \
    MKT(K, pxg, u0##S, u1##S, u2##S, u3##S, i0, i1, i2, i3);                 \
    MKT(K, 8 + pxg, u4##S, u5##S, u6##S, u7##S, i4, i5, i6, i7);             \
    r0##S = *(const half8*)(xhb + i0);                                       \
    r1##S = *(const half8*)(xhb + i1);                                       \
    r2##S = *(const half8*)(xhb + i2);                                       \
    r3##S = *(const half8*)(xhb + i3);                                       \
    r4##S = *(const half8*)(xhb + i4);                                       \
    r5##S = *(const half8*)(xhb + i5);                                       \
    r6##S = *(const half8*)(xhb + i6);                                       \
    r7##S = *(const half8*)(xhb + i7);                                       \
} while (0)

#define BW(K, S) do {                                                        \
    half8 bfA = r0##S * SPLAT8((_Float16)u0##S);                             \
    bfA = bfA + r1##S * SPLAT8((_Float16)u1##S);                             \
    bfA = bfA + r2##S * SPLAT8((_Float16)u2##S);                             \
    bfA = bfA + r3##S * SPLAT8((_Float16)u3##S);                             \
    half8 bfB = r4##S * SPLAT8((_Float16)u4##S);                             \
    bfB = bfB + r5##S * SPLAT8((_Float16)u5##S);                             \
    bfB = bfB + r6##S * SPLAT8((_Float16)u6##S);                             \
    bfB = bfB + r7##S * SPLAT8((_Float16)u7##S);                             \
    _Float16* bb = bbw + (((K) & 1) << 10);                                  \
    *(half8*)&bb[(pxg << 6) + ((oct ^ pxg) << 3)] = bfA;                     \
    *(half8*)&bb[((8 + pxg) << 6) + ((oct ^ pxg) << 3)] = bfB;               \
} while (0)

#define CONS(K) do {                                                         \
    const _Float16* bbr = bbw + (((K) & 1) << 10);                           \
    half8 bf = *(const half8*)&bbr[(pl << 6) + ((g ^ (pl & 7)) << 3)];       \
    half8 bd = *(const half8*)&bbr[(pl << 6) + (((g + 4) ^ (pl & 7)) << 3)]; \
    const _Float16* wk = waf + ((K) << 12) + lane * 8;                       \
    half8 q0 = *(const half8*)(wk + (0 << 9));                               \
    half8 q1 = *(const half8*)(wk + (1 << 9));                               \
    half8 q2 = *(const half8*)(wk + (2 << 9));                               \
    half8 q3 = *(const half8*)(wk + (3 << 9));                               \
    half8 q4 = *(const half8*)(wk + (4 << 9));                               \
    half8 q5 = *(const half8*)(wk + (5 << 9));                               \
    half8 q6 = *(const half8*)(wk + (6 << 9));                               \
    half8 q7 = *(const half8*)(wk + (7 << 9));                               \
    MF(q0, bf, acc0); MF(q1, bf, acc1); MF(q2, bf, acc2); MF(q3, bf, acc3);  \
    MF(q4, bd, acc0); MF(q5, bd, acc1); MF(q6, bd, acc2); MF(q7, bd, acc3);  \
} while (0)

#define ITER(K, S) do {                                                      \
    const _Float16* bbr = bbw + (((K) & 1) << 10);                           \
    half8 bf = *(const half8*)&bbr[(pl << 6) + ((g ^ (pl & 7)) << 3)];       \
    half8 bd = *(const half8*)&bbr[(pl << 6) + (((g + 4) ^ (pl & 7)) << 3)]; \
    GLOAD((K) + 1, S);                                                       \
    const _Float16* wk = waf + ((K) << 12) + lane * 8;                       \
    half8 q0 = *(const half8*)(wk + (0 << 9));                               \
    half8 q1 = *(const half8*)(wk + (1 << 9));                               \
    half8 q2 = *(const half8*)(wk + (2 << 9));                               \
    half8 q3 = *(const half8*)(wk + (3 << 9));                               \
    half8 q4 = *(const half8*)(wk + (4 << 9));                               \
    half8 q5 = *(const half8*)(wk + (5 << 9));                               \
    half8 q6 = *(const half8*)(wk + (6 << 9));                               \
    half8 q7 = *(const half8*)(wk + (7 << 9));                               \
    MF(q0, bf, acc0); MF(q1, bf, acc1); MF(q2, bf, acc2); MF(q3, bf, acc3);  \
    MF(q4, bd, acc0); MF(q5, bd, acc1); MF(q6, bd, acc2); MF(q7, bd, acc3);  \
    BW((K) + 1, S);                                                          \
} while (0)

    {
        DECLG(A)
        DECLG(B)
        GLOAD(0, A);
        BW(0, A);
        ITER(0, B);
        ITER(1, A);
        ITER(2, B);
        ITER(3, A);
        ITER(4, B);
        ITER(5, A);
        ITER(6, B);
        ITER(7, A);
        CONS(8);
    }

    // epilogue: D col = pl, row o = m*16 + g*4 + j
    float* outp = out + (size_t)b * OO * HWsz + h * WW + p0 + s * 16 + pl;
#pragma unroll
    for (int j = 0; j < 4; ++j) outp[(size_t)(g * 4 + j) * HWsz] = acc0[j];
#pragma unroll
    for (int j = 0; j < 4; ++j) outp[(size_t)(16 + g * 4 + j) * HWsz] = acc1[j];
#pragma unroll
    for (int j = 0; j < 4; ++j) outp[(size_t)(32 + g * 4 + j) * HWsz] = acc2[j];
#pragma unroll
    for (int j = 0; j < 4; ++j) outp[(size_t)(48 + g * 4 + j) * HWsz] = acc3[j];
}

extern "C" void kernel_launch(void* const* d_in, const int* in_sizes, int n_in,
                              void* d_out, int out_size, void* d_ws, size_t ws_size,
                              hipStream_t stream)
{
    const float* x   = (const float*)d_in[0];
    const float* ow  = (const float*)d_in[1];
    const float* ob  = (const float*)d_in[2];
    const float* mw  = (const float*)d_in[3];
    const float* mb  = (const float*)d_in[4];
    const float* wgt = (const float*)d_in[5];
    float* out = (float*)d_out;

    // ws: xh (4*16384*64 f16 = 8.39MB) | waf (36864 f16) | wcf (18432 f16)
    _Float16* xh  = (_Float16*)d_ws;
    _Float16* waf = xh + (size_t)BB * HWsz * 64;
    _Float16* wcf = waf + 36864;

    pre_kernel<<<dim3(512 + 216), dim3(256), 0, stream>>>(
        x, wgt, ow, mw, xh, waf, wcf);
    fused_kernel<<<dim3(256), dim3(1024), 0, stream>>>(
        xh, waf, wcf, ob, mb, out);
}

// Round 21
// 37.426 us; speedup vs baseline: 1.2827x; 1.2827x over previous
//
#include <hip/hip_runtime.h>
#include <math.h>

#define BB 4
#define CC 64
#define OO 64
#define HH 128
#define WW 128
#define HWsz (HH * WW)

typedef __attribute__((ext_vector_type(8))) _Float16 half8;
typedef __attribute__((ext_vector_type(4))) float floatx4;

// ---------------------------------------------------------------------------
// pre: (blocks 0..511)  x NCHW f32 -> xh merged NHWC f16 (px = 128B = 1 line)
//      (blocks 512..727) fragment-ordered f16 weight repack:
//  waf[((k*2+kh)*4+m)*512 + lane*8 + j], wcf[((k*2+kh)*2+m)*512 + lane*8 + j]
//  (waf and wcf are CONTIGUOUS in ws -> fused kernel stages both in one copy)
// ---------------------------------------------------------------------------
__global__ __launch_bounds__(256) void pre_kernel(
    const float* __restrict__ x, const float* __restrict__ wgt,
    const float* __restrict__ ow, const float* __restrict__ mw,
    _Float16* __restrict__ xh, _Float16* __restrict__ waf,
    _Float16* __restrict__ wcf)
{
    int bid = blockIdx.x;
    int tid = threadIdx.x;
    if (bid < 512) {
        int b = bid >> 7, y = bid & 127;
        int px = tid & 127;
        int ch = (tid >> 7) * 32;
        const float* xp = x + (size_t)(b * CC + ch) * HWsz + y * WW + px;
        _Float16 buf[32];
#pragma unroll
        for (int q = 0; q < 32; ++q)
            buf[q] = (_Float16)xp[(size_t)q * HWsz];
        _Float16* dst = xh + ((size_t)(b * HH + y) * WW + px) * 64 + ch;
#pragma unroll
        for (int q = 0; q < 4; ++q)
            *(half8*)&dst[q * 8] = *(const half8*)&buf[q * 8];
    } else {
        int i = (bid - 512) * 256 + tid;
        if (i < 36864) {
            int j = i & 7, lane = (i >> 3) & 63, rest = i >> 9;
            int m = rest & 3, kh = (rest >> 2) & 1, k = rest >> 3;
            int o = m * 16 + (lane & 15);
            int c = kh * 32 + ((lane >> 4) << 3) + j;
            waf[i] = (_Float16)wgt[o * 576 + c * 9 + k];
        } else if (i < 55296) {
            int t = i - 36864;
            int j = t & 7, lane = (t >> 3) & 63, rest = t >> 9;
            int m = rest & 1, kh = (rest >> 1) & 1, k = rest >> 2;
            int o = m * 16 + (lane & 15);
            int c = kh * 32 + ((lane >> 4) << 3) + j;
            float v = 0.f;
            if (o < 18) v = ow[o * 576 + c * 9 + k];
            else if (o < 27) v = mw[(o - 18) * 576 + c * 9 + k];
            wcf[t] = (_Float16)v;
        }
    }
}

// ---------------------------------------------------------------------------
// fused kernel (fp16): ALL weights in LDS, full-line loads for BOTH phases.
// 256 blocks x 1024 thr = 1 block/CU; 16 waves = 4 rows x 4 strips x 64-px
// column half.
//   stage:   waf+wcf (110.6KB) global -> LDS cooperatively; ONE barrier.
//   phase 1: per conv row ky: stage the wave's 18-col input row as FULL
//            128B lines (3 instr = 18 L1 visits vs 96) into the wave-private
//            bounce buffer; 3 taps read fragments from LDS; weights from LDS.
//   phase 2: R18 within-tap bounce (full-line gathers, 1 visit/px-corner),
//            weights from LDS. L1 visits/block: ~19K -> ~11K.
// LDS: 110592(w) + 13824(om) + 36864(bounce) = 161280 B (<= 160 KiB).
// ---------------------------------------------------------------------------
__global__ __launch_bounds__(1024, 1) void fused_kernel(
    const _Float16* __restrict__ wsrc, const _Float16* __restrict__ xh,
    const float* __restrict__ ob, const float* __restrict__ mb,
    float* __restrict__ out)
{
    __shared__ __align__(16) _Float16 lds_w[55296];      // waf | wcf
    __shared__ _Float16 omh[16 * 27 * 16];               // 13824 B
    __shared__ __align__(16) _Float16 bounce[16 * 1152]; // 36864 B

    int tid = threadIdx.x;
    int gid = blockIdx.x;
    // XCD swizzle: 256 blocks = 8 XCDs x 32 contiguous region-tiles
    int sid = (gid & 7) * 32 + (gid >> 3);
    int b = sid >> 6;
    int t = sid & 63;
    int rq = t >> 1;
    int q = t & 1;

    int wv = tid >> 6;         // 0..15
    int lane = tid & 63;
    int s = wv & 3;            // strip
    int h = rq * 4 + (wv >> 2);
    int p0 = q << 6;
    int g = lane >> 4;
    int pl = lane & 15;
    int oct = lane & 7;        // full-line role: channel octet
    int pxg = lane >> 3;       // full-line role: pixel within 8-px group

    const _Float16* xhb = xh + ((size_t)b << 20);
    _Float16* omw = &omh[wv * 27 * 16];
    _Float16* bbw = &bounce[wv * 1152];

    // ---- cooperative weight stage: 55296 halfs = 6912 chunks of 16B -------
#pragma unroll
    for (int it = 0; it < 7; ++it) {
        int c = it * 1024 + tid;
        if (c < 6912)
            *(half8*)&lds_w[c * 8] = *(const half8*)(wsrc + c * 8);
    }
    __syncthreads();

    // ---------------- phase 1: conv via full-line row staging --------------
    floatx4 accC0 = {0.f, 0.f, 0.f, 0.f};
    floatx4 accC1 = {0.f, 0.f, 0.f, 0.f};

#define STAGE_ROW(KY) do {                                                   \
    int gy = h + (KY) - 1;                                                   \
    half8 z = {0, 0, 0, 0, 0, 0, 0, 0};                                      \
    _Pragma("unroll") for (int j = 0; j < 3; ++j) {                          \
        int pxi = j * 8 + pxg;                                               \
        bool act = (j < 2) | (pxg < 2);                                      \
        int col = p0 + s * 16 - 1 + pxi;                                     \
        bool val = act & (gy >= 0) & (gy < HH) & (col >= 0) & (col < WW);    \
        half8 v = z;                                                         \
        if (val)                                                             \
            v = *(const half8*)(xhb + (((size_t)gy * WW + col) << 6) + oct * 8); \
        if (act)                                                             \
            *(half8*)&bbw[(pxi << 6) + ((oct ^ (pxi & 7)) << 3)] = v;        \
    }                                                                        \
} while (0)

#define CONVT(KY, KX) do {                                                   \
    int K = (KY) * 3 + (KX);                                                 \
    int pc = pl + (KX);                                                      \
    half8 a0 = *(const half8*)&bbw[(pc << 6) + ((g ^ (pc & 7)) << 3)];       \
    half8 a1 = *(const half8*)&bbw[(pc << 6) + (((g + 4) ^ (pc & 7)) << 3)]; \
    const _Float16* wp = &lds_w[36864 + (K << 11) + lane * 8];               \
    half8 w00 = *(const half8*)(wp + (0 << 9));                              \
    half8 w01 = *(const half8*)(wp + (1 << 9));                              \
    half8 w10 = *(const half8*)(wp + (2 << 9));                              \
    half8 w11 = *(const half8*)(wp + (3 << 9));                              \
    accC0 = __builtin_amdgcn_mfma_f32_16x16x32_f16(w00, a0, accC0, 0, 0, 0); \
    accC1 = __builtin_amdgcn_mfma_f32_16x16x32_f16(w01, a0, accC1, 0, 0, 0); \
    accC0 = __builtin_amdgcn_mfma_f32_16x16x32_f16(w10, a1, accC0, 0, 0, 0); \
    accC1 = __builtin_amdgcn_mfma_f32_16x16x32_f16(w11, a1, accC1, 0, 0, 0); \
} while (0)

    STAGE_ROW(0); CONVT(0, 0); CONVT(0, 1); CONVT(0, 2);
    STAGE_ROW(1); CONVT(1, 0); CONVT(1, 1); CONVT(1, 2);
    STAGE_ROW(2); CONVT(2, 0); CONVT(2, 1); CONVT(2, 2);

    // om epilogue (wave-local, f16)
#pragma unroll
    for (int j = 0; j < 4; ++j) {
        int o = g * 4 + j;
        omw[o * 16 + pl] = (_Float16)(accC0[j] + ob[o]);
        int o2 = 16 + g * 4 + j;
        float v = accC1[j];
        if (o2 < 18) omw[o2 * 16 + pl] = (_Float16)(v + ob[o2]);
        else if (o2 < 27)
            omw[o2 * 16 + pl] =
                (_Float16)(1.0f / (1.0f + expf(-(v + mb[o2 - 18]))));
    }

    // ---------------- phase 2: full-line gathers + LDS bounce + GEMM -------
    floatx4 acc0 = {0.f, 0.f, 0.f, 0.f}, acc1 = {0.f, 0.f, 0.f, 0.f};
    floatx4 acc2 = {0.f, 0.f, 0.f, 0.f}, acc3 = {0.f, 0.f, 0.f, 0.f};

#define MKT(K, P, U00, U01, U10, U11, I00, I01, I10, I11) do {               \
    int ky = (K) / 3, kx = (K) - ky * 3;                                     \
    float oy = (float)omw[(2 * (K)) * 16 + (P)];                             \
    float ox = (float)omw[(2 * (K) + 1) * 16 + (P)];                         \
    float mk = (float)omw[(18 + (K)) * 16 + (P)];                            \
    float py = oy + (float)(h + ky - 1);                                     \
    float qx = ox + (float)(p0 + s * 16 + (P) + kx - 1);                     \
    float y0f = floorf(py), x0f = floorf(qx);                                \
    float dyy = py - y0f, dxx = qx - x0f;                                    \
    int y0 = (int)y0f, x0 = (int)x0f;                                        \
    int y1 = y0 + 1, x1 = x0 + 1;                                            \
    bool vy0 = (y0 >= 0) & (y0 < HH), vy1 = (y1 >= 0) & (y1 < HH);           \
    bool vx0 = (x0 >= 0) & (x0 < WW), vx1 = (x1 >= 0) & (x1 < WW);           \
    U00 = (vy0 & vx0) ? (1.f - dyy) * (1.f - dxx) * mk : 0.f;                \
    U01 = (vy0 & vx1) ? (1.f - dyy) * dxx * mk : 0.f;                        \
    U10 = (vy1 & vx0) ? dyy * (1.f - dxx) * mk : 0.f;                        \
    U11 = (vy1 & vx1) ? dyy * dxx * mk : 0.f;                                \
    int yc0 = min(max(y0, 0), HH - 1), yc1 = min(max(y1, 0), HH - 1);        \
    int xc0 = min(max(x0, 0), WW - 1), xc1 = min(max(x1, 0), WW - 1);        \
    I00 = ((yc0 * WW + xc0) << 6) + oct * 8;                                 \
    I01 = ((yc0 * WW + xc1) << 6) + oct * 8;                                 \
    I10 = ((yc1 * WW + xc0) << 6) + oct * 8;                                 \
    I11 = ((yc1 * WW + xc1) << 6) + oct * 8;                                 \
} while (0)

#define SPLAT8(H) ((half8){(H), (H), (H), (H), (H), (H), (H), (H)})
#define MF(Q, B, A) A = __builtin_amdgcn_mfma_f32_16x16x32_f16(Q, B, A, 0, 0, 0)

#define TAP(K) do {                                                          \
    float uA0, uA1, uA2, uA3, uB0, uB1, uB2, uB3;                            \
    int iA0, iA1, iA2, iA3, iB0, iB1, iB2, iB3;                              \
    MKT(K, pxg, uA0, uA1, uA2, uA3, iA0, iA1, iA2, iA3);                     \
    MKT(K, 8 + pxg, uB0, uB1, uB2, uB3, iB0, iB1, iB2, iB3);                 \
    half8 a0 = *(const half8*)(xhb + iA0);                                   \
    half8 a1 = *(const half8*)(xhb + iA1);                                   \
    half8 a2 = *(const half8*)(xhb + iA2);                                   \
    half8 a3 = *(const half8*)(xhb + iA3);                                   \
    half8 e0 = *(const half8*)(xhb + iB0);                                   \
    half8 e1 = *(const half8*)(xhb + iB1);                                   \
    half8 e2 = *(const half8*)(xhb + iB2);                                   \
    half8 e3 = *(const half8*)(xhb + iB3);                                   \
    half8 bfA = a0 * SPLAT8((_Float16)uA0);                                  \
    bfA = bfA + a1 * SPLAT8((_Float16)uA1);                                  \
    bfA = bfA + a2 * SPLAT8((_Float16)uA2);                                  \
    bfA = bfA + a3 * SPLAT8((_Float16)uA3);                                  \
    half8 bfB = e0 * SPLAT8((_Float16)uB0);                                  \
    bfB = bfB + e1 * SPLAT8((_Float16)uB1);                                  \
    bfB = bfB + e2 * SPLAT8((_Float16)uB2);                                  \
    bfB = bfB + e3 * SPLAT8((_Float16)uB3);                                  \
    *(half8*)&bbw[(pxg << 6) + ((oct ^ pxg) << 3)] = bfA;                    \
    *(half8*)&bbw[((8 + pxg) << 6) + ((oct ^ pxg) << 3)] = bfB;              \
    half8 bf = *(const half8*)&bbw[(pl << 6) + ((g ^ (pl & 7)) << 3)];       \
    half8 bd = *(const half8*)&bbw[(pl << 6) + (((g + 4) ^ (pl & 7)) << 3)]; \
    const _Float16* wk = &lds_w[((K) << 12) + lane * 8];                     \
    half8 q0 = *(const half8*)(wk + (0 << 9));                               \
    half8 q1 = *(const half8*)(wk + (1 << 9));                               \
    half8 q2 = *(const half8*)(wk + (2 << 9));                               \
    half8 q3 = *(const half8*)(wk + (3 << 9));                               \
    half8 q4 = *(const half8*)(wk + (4 << 9));                               \
    half8 q5 = *(const half8*)(wk + (5 << 9));                               \
    half8 q6 = *(const half8*)(wk + (6 << 9));                               \
    half8 q7 = *(const half8*)(wk + (7 << 9));                               \
    MF(q0, bf, acc0); MF(q1, bf, acc1); MF(q2, bf, acc2); MF(q3, bf, acc3);  \
    MF(q4, bd, acc0); MF(q5, bd, acc1); MF(q6, bd, acc2); MF(q7, bd, acc3);  \
} while (0)

    TAP(0); TAP(1); TAP(2); TAP(3); TAP(4); TAP(5); TAP(6); TAP(7); TAP(8);

    // epilogue: D col = pl, row o = m*16 + g*4 + j
    float* outp = out + (size_t)b * OO * HWsz + h * WW + p0 + s * 16 + pl;
#pragma unroll
    for (int j = 0; j < 4; ++j) outp[(size_t)(g * 4 + j) * HWsz] = acc0[j];
#pragma unroll
    for (int j = 0; j < 4; ++j) outp[(size_t)(16 + g * 4 + j) * HWsz] = acc1[j];
#pragma unroll
    for (int j = 0; j < 4; ++j) outp[(size_t)(32 + g * 4 + j) * HWsz] = acc2[j];
#pragma unroll
    for (int j = 0; j < 4; ++j) outp[(size_t)(48 + g * 4 + j) * HWsz] = acc3[j];
}

extern "C" void kernel_launch(void* const* d_in, const int* in_sizes, int n_in,
                              void* d_out, int out_size, void* d_ws, size_t ws_size,
                              hipStream_t stream)
{
    const float* x   = (const float*)d_in[0];
    const float* ow  = (const float*)d_in[1];
    const float* ob  = (const float*)d_in[2];
    const float* mw  = (const float*)d_in[3];
    const float* mb  = (const float*)d_in[4];
    const float* wgt = (const float*)d_in[5];
    float* out = (float*)d_out;

    // ws: xh (4*16384*64 f16 = 8.39MB) | waf (36864 f16) | wcf (18432 f16)
    //                                     ^-- contiguous: staged as one copy
    _Float16* xh  = (_Float16*)d_ws;
    _Float16* waf = xh + (size_t)BB * HWsz * 64;
    _Float16* wcf = waf + 36864;

    pre_kernel<<<dim3(512 + 216), dim3(256), 0, stream>>>(
        x, wgt, ow, mw, xh, waf, wcf);
    fused_kernel<<<dim3(256), dim3(1024), 0, stream>>>(
        waf, xh, ob, mb, out);
}